// Round 3
// baseline (77.048 us; speedup 1.0000x reference)
//
#include <hip/hip_runtime.h>

// MOLGCirculantLinear: fused circular-conv (k=8) + poly + clamp + scale + photodetect.
// x[512][1024] f32, weight[128][128][8] f32, scale[64][8] f32.
// d_out = out[512][1024] (524288 f32) ++ phase[512][128][128][8].
//
// Layout: one wave per (b, gy). Lane i owns (gx_sub = i>>1, k-half = i&1):
// computes 4 conv outputs, so each phase store instruction writes a fully
// contiguous, line-aligned 1KB burst (lane i -> byte 16*i). 4 iterations
// cover gx in [0,128). Avoids the half-line interleaved store pattern of R0.

#define NB    512
#define NGY   128
#define NGX   128
#define NK    8

typedef float f32x4 __attribute__((ext_vector_type(4)));

__global__ __launch_bounds__(256, 4) void molg_fused(
    const float* __restrict__ x,
    const float* __restrict__ w,
    const float* __restrict__ scale,
    float* __restrict__ d_out)
{
    const int lane = threadIdx.x & 63;
    const int wave = threadIdx.x >> 6;
    const int pair = blockIdx.x;            // 0 .. 512*32-1
    const int b    = pair >> 5;
    const int gy   = ((pair & 31) << 2) + wave;

    const int gxs = lane >> 1;              // 0..31: gx base within iteration
    const int kq  = lane & 1;               // which float4 of the 8 k-values

    float* out   = d_out;
    float* phase = d_out + (size_t)NB * NGY * NK;   // +524288

    const float c0 = 0.02403f, c1 = -0.2699f, c2 = 1.17f,
                c3 = -2.454f,  c4 = 2.523f,  c5 = -0.08003f;

    // preload scale: gx & 63 alternates between gxs and gxs+32 across iterations
    const float4 s_even = *reinterpret_cast<const float4*>(scale + (size_t)gxs * NK + 4 * kq);
    const float4 s_odd  = *reinterpret_cast<const float4*>(scale + (size_t)(gxs + 32) * NK + 4 * kq);

    float acc[4] = {0.f, 0.f, 0.f, 0.f};

#pragma unroll
    for (int it = 0; it < 4; ++it) {
        const int gx = 32 * it + gxs;

        // x^2 for this gx (lane pairs load the same 32B; L1 broadcast)
        const float4* x4 = reinterpret_cast<const float4*>(x + (size_t)b * 1024 + gx * NK);
        float4 xa = x4[0], xb = x4[1];
        float x2[NK] = {xa.x * xa.x, xa.y * xa.y, xa.z * xa.z, xa.w * xa.w,
                        xb.x * xb.x, xb.y * xb.y, xb.z * xb.z, xb.w * xb.w};

        // rotate by 4*kq so conv indices are compile-time: y[t] = x2[(t + 4*kq) & 7]
        float y[NK];
#pragma unroll
        for (int t = 0; t < NK; ++t)
            y[t] = kq ? x2[(t + 4) & 7] : x2[t];

        // weights for this gx
        const float4* w4 = reinterpret_cast<const float4*>(w + ((size_t)gy * NGX + gx) * NK);
        float4 wa = w4[0], wb = w4[1];
        float wv[NK] = {wa.x, wa.y, wa.z, wa.w, wb.x, wb.y, wb.z, wb.w};

        // 4 conv outputs: xr[j] = sum_m wv[m] * x2[(j + 4*kq - m) & 7] = sum_m wv[m]*y[(j-m)&7]
        float xr[4];
#pragma unroll
        for (int j = 0; j < 4; ++j) {
            float s = 0.f;
#pragma unroll
            for (int m = 0; m < NK; ++m)
                s = fmaf(wv[m], y[(j - m) & 7], s);
            xr[j] = s;
        }

        // phase store: lane i -> byte offset 16*i of the wave's 1KB chunk (fully dense)
        float* pbase = phase + (((size_t)b * NGY + gy) * NGX + 32 * it) * NK;
        f32x4 pv = {xr[0], xr[1], xr[2], xr[3]};
        __builtin_nontemporal_store(pv, reinterpret_cast<f32x4*>(pbase) + lane);

        // poly -> clamp -> * scale -> accumulate
        const float4 sv4 = (it & 1) ? s_odd : s_even;
        const float sv[4] = {sv4.x, sv4.y, sv4.z, sv4.w};
#pragma unroll
        for (int j = 0; j < 4; ++j) {
            float p = fmaf(c0, xr[j], c1);
            p = fmaf(p, xr[j], c2);
            p = fmaf(p, xr[j], c3);
            p = fmaf(p, xr[j], c4);
            p = fmaf(p, xr[j], c5);
            p = fminf(fmaxf(p, 0.f), 1.f);
            acc[j] = fmaf(p, sv[j], acc[j]);
        }
    }

    // reduce over same-parity lanes (32 of them): strides 2,4,8,16,32 preserve kq
#pragma unroll
    for (int off = 2; off < 64; off <<= 1) {
#pragma unroll
        for (int j = 0; j < 4; ++j)
            acc[j] += __shfl_xor(acc[j], off, 64);
    }

    // lane 0 (kq=0) writes k 0..3, lane 1 (kq=1) writes k 4..7
    if (lane < 2) {
        float4* o4 = reinterpret_cast<float4*>(out + (size_t)b * 1024 + gy * NK) + lane;
        *o4 = make_float4(2.f * acc[0] - 128.f, 2.f * acc[1] - 128.f,
                          2.f * acc[2] - 128.f, 2.f * acc[3] - 128.f);
    }
}

extern "C" void kernel_launch(void* const* d_in, const int* in_sizes, int n_in,
                              void* d_out, int out_size, void* d_ws, size_t ws_size,
                              hipStream_t stream) {
    const float* x     = (const float*)d_in[0];   // 512*1024
    const float* w     = (const float*)d_in[1];   // 128*128*8
    const float* scale = (const float*)d_in[2];   // 64*8
    float* out = (float*)d_out;

    dim3 grid(NB * (NGY / 4));   // 16384 blocks, one wave per (b, gy)
    dim3 block(256);
    hipLaunchKernelGGL(molg_fused, grid, block, 0, stream, x, w, scale, out);
}